// Round 9
// baseline (190.531 us; speedup 1.0000x reference)
//
#include <hip/hip_runtime.h>
#include <hip/hip_bf16.h>

#define B_ 16
#define N_ 2000
#define E_ 8000
#define P_ 16000
#define XROW (E_ + N_)   // 10000 rows per batch in x
#define OROW (P_ + N_)   // 18000 rows per batch in out
#define PAIR0 18560      // k_pre: first thread index of the edge-pairing branch

typedef __hip_bfloat16 bf16;
typedef unsigned short u16;
typedef unsigned int u32;
typedef __attribute__((ext_vector_type(8))) short short8;   // 8 bf16 in 4 VGPRs
typedef __attribute__((ext_vector_type(4))) float f32x4;
typedef __attribute__((ext_vector_type(4))) unsigned int u32x4;    // nt-store-able
typedef __attribute__((ext_vector_type(4))) unsigned short u16x4;  // nt-store-able

__device__ __forceinline__ float b2f(bf16 v) { return __bfloat162float(v); }
__device__ __forceinline__ float u2f(u16 u) { return __uint_as_float(((u32)u) << 16); }
__device__ __forceinline__ float lo2f(u32 u) { return __uint_as_float(u << 16); }
__device__ __forceinline__ float hi2f(u32 u) { return __uint_as_float(u & 0xFFFF0000u); }
__device__ __forceinline__ u16 f2bu(float v) {
  bf16 b = __float2bfloat16(v);
  return *reinterpret_cast<u16*>(&b);
}

// dtype-agnostic input load
__device__ __forceinline__ float ldin(const void* p, int i, int f32) {
  return f32 ? ((const float*)p)[i] : __bfloat162float(((const bf16*)p)[i]);
}

// dtype self-detect: view first 512B of x as bf16; f32 data shows ~70%
// wild/non-finite values in the low halves. Run ONCE in k_pre (R5).
__device__ __forceinline__ int detect_f32(const void* x) {
  int lane = threadIdx.x & 63;
  ushort4 v = reinterpret_cast<const ushort4*>(x)[lane];
  int bad = 0;
  float f0 = u2f(v.x), f1 = u2f(v.y), f2 = u2f(v.z), f3 = u2f(v.w);
  if (!(fabsf(f0) < 1e4f)) bad++;
  if (!(fabsf(f1) < 1e4f)) bad++;
  if (!(fabsf(f2) < 1e4f)) bad++;
  if (!(fabsf(f3) < 1e4f)) bad++;
  unsigned long long m = __ballot(bad > 0);
  return __popcll(m) > 8;
}

// 8 consecutive input elems -> short8 of bf16 (A-fragment load)
__device__ __forceinline__ short8 ld8b(const void* p, size_t i, int f32) {
  short8 r;
  if (f32) {
    const float* f = (const float*)p + i;
    float4 v0 = *reinterpret_cast<const float4*>(f);
    float4 v1 = *reinterpret_cast<const float4*>(f + 4);
    u16* o = (u16*)&r;
    o[0] = f2bu(v0.x); o[1] = f2bu(v0.y); o[2] = f2bu(v0.z); o[3] = f2bu(v0.w);
    o[4] = f2bu(v1.x); o[5] = f2bu(v1.y); o[6] = f2bu(v1.z); o[7] = f2bu(v1.w);
  } else {
    r = *reinterpret_cast<const short8*>((const u16*)p + i);
  }
  return r;
}

// ---------- Kernel A: weight precompute + rowptr + flag + edge pairing -------
// Wtn[c][k] (192x64): c<64 -> W_node^T; c<128 -> (W_node@W1)^T; else (W_node@W3)^T
// Wte[c][k] (64x64): (W_edge@W2)^T.
// c1 = b_node@W1 + b_comb (bias fold).  c3 = b_node@W3.
// rowptr[n] = lower_bound(src, n).  flags[0] = f32 dtype flag.
// epair[e] = (u, v, p0, p1): the two directed positions of undirected edge e.
// p1 found by binary search over the sorted key src*N+dst (row-major nonzero
// order) — no dependency on rowptr, so no intra-launch race.
__global__ __launch_bounds__(256) void k_pre(
    const void* __restrict__ x,
    const void* __restrict__ W_edge, const void* __restrict__ W_node,
    const void* __restrict__ b_node, const void* __restrict__ W_comb,
    const void* __restrict__ b_comb,
    const int* __restrict__ src, const int* __restrict__ dst,
    const int* __restrict__ eidx,
    u16* __restrict__ Wtn, u16* __restrict__ Wte,
    float* __restrict__ c1, float* __restrict__ c3,
    int* __restrict__ rowptr, int* __restrict__ flags,
    int4* __restrict__ epair) {
  const int f32 = detect_f32(x);
  int o = blockIdx.x * 256 + threadIdx.x;
  if (o < 4096) {
    int c = o >> 6, k = o & 63;
    Wtn[c*64 + k] = f2bu(ldin(W_node, k*64 + c, f32));
  } else if (o < 12288) {
    int oo = o - 4096;            // [0, 8192)
    int cc = oo >> 6, k = oo & 63;
    int col = cc & 63;
    int base = (cc < 64) ? 0 : 128;
    float a = 0.f;
    for (int j = 0; j < 64; ++j)
      a += ldin(W_node, k*64 + j, f32) * ldin(W_comb, (base + j)*64 + col, f32);
    Wtn[(64 + cc)*64 + k] = f2bu(a);
  } else if (o < 16384) {
    int oo = o - 12288;
    int c = oo >> 6, k = oo & 63;
    float a = 0.f;
    for (int j = 0; j < 64; ++j)
      a += ldin(W_edge, k*64 + j, f32) * ldin(W_comb, (64 + j)*64 + c, f32);
    Wte[c*64 + k] = f2bu(a);
  } else if (o < 16448) {
    int j = o - 16384;
    float a = ldin(b_comb, j, f32);               // b_comb fold
    for (int k = 0; k < 64; ++k) a += ldin(b_node, k, f32) * ldin(W_comb, k*64 + j, f32);
    c1[j] = a;
  } else if (o < 16512) {
    int j = o - 16448;
    float a = 0.f;
    for (int k = 0; k < 64; ++k) a += ldin(b_node, k, f32) * ldin(W_comb, (128 + k)*64 + j, f32);
    c3[j] = a;
  } else if (o < 16512 + N_ + 1) {
    int n = o - 16512;
    int lo = 0, hi = P_;
    while (lo < hi) { int mid = (lo + hi) >> 1; if (src[mid] < n) lo = mid + 1; else hi = mid; }
    rowptr[n] = lo;
  } else if (o == 16512 + N_ + 1) {
    flags[0] = f32;
  } else if (o >= PAIR0 && o < PAIR0 + P_) {
    int p = o - PAIR0;
    int u = src[p], v = dst[p];
    if (u < v) {                                   // canonical direction
      int e = eidx[p];
      long key = (long)v * N_ + u;                 // position of (v,u)
      int lo = 0, hi = P_ - 1;
      while (lo < hi) {
        int mid = (lo + hi) >> 1;
        long k2 = (long)src[mid] * N_ + dst[mid];
        if (k2 < key) lo = mid + 1; else hi = mid;
      }
      int4 pr; pr.x = u; pr.y = v; pr.z = p; pr.w = lo;
      epair[e] = pr;
    }
  }
}

// ---------- Kernel B: fused node+edge transform, MFMA, LDS-free ----------
// blocks [0,500): node rows, 64/block (4 waves x 16 rows), 12 col-tiles:
//   h(64ch, stride 64) and hsd(interleaved [hs|hd], stride 128) = X @ Wn
// blocks [500,1500): edge rows, 128/block (4 waves x 32 rows), 4 col-tiles:
//   fe(128x64) = X @ A2
__global__ __launch_bounds__(256) void k_transform(
    const void* __restrict__ x, const int* __restrict__ flags,
    const u16* __restrict__ Wtn, const u16* __restrict__ Wte,
    const void* __restrict__ b_node,
    const float* __restrict__ c1, const float* __restrict__ c3,
    bf16* __restrict__ h, bf16* __restrict__ hsd, bf16* __restrict__ fe) {
  const int f32 = flags[0];
  int t = threadIdx.x;
  int wave = t >> 6, lane = t & 63;
  int m16 = lane & 15, q = lane >> 4;
  if (blockIdx.x < 500) {
    int row0 = blockIdx.x * 64 + wave * 16;
    int arow = row0 + m16;
    int b = arow / N_, n = arow - b * N_;
    size_t xbase = (size_t)(b * XROW + E_ + n) * 64;
    short8 af0 = ld8b(x, xbase + q*8, f32);
    short8 af1 = ld8b(x, xbase + 32 + q*8, f32);
    f32x4 acc[12];
    #pragma unroll
    for (int c = 0; c < 12; ++c) acc[c] = (f32x4){0.f, 0.f, 0.f, 0.f};
    #pragma unroll
    for (int c = 0; c < 12; ++c) {
      short8 b0 = *reinterpret_cast<const short8*>(&Wtn[(c*16 + m16)*64 + q*8]);
      short8 b1 = *reinterpret_cast<const short8*>(&Wtn[(c*16 + m16)*64 + 32 + q*8]);
      acc[c] = __builtin_amdgcn_mfma_f32_16x16x32_bf16(af0, b0, acc[c], 0, 0, 0);
      acc[c] = __builtin_amdgcn_mfma_f32_16x16x32_bf16(af1, b1, acc[c], 0, 0, 0);
    }
    // D: col = m16 (within tile), row = q*4 + r
    #pragma unroll
    for (int c = 0; c < 12; ++c) {
      int seg = c >> 2;             // 0:h 1:hs(hsd+0) 2:hd(hsd+64)
      int lcol = (c*16 + m16) & 63;
      float bias = (seg == 0) ? ldin(b_node, lcol, f32) : (seg == 1 ? c1[lcol] : c3[lcol]);
      #pragma unroll
      for (int r = 0; r < 4; ++r) {
        int row = row0 + q*4 + r;
        bf16 val = __float2bfloat16(acc[c][r] + bias);
        if (seg == 0) h[(size_t)row*64 + lcol] = val;
        else          hsd[(size_t)row*128 + (seg == 2 ? 64 : 0) + lcol] = val;
      }
    }
  } else {
    int row0 = (blockIdx.x - 500) * 128 + wave * 32;
    short8 af[2][2];
    #pragma unroll
    for (int rt = 0; rt < 2; ++rt) {
      int arow = row0 + rt*16 + m16;
      int b = arow / E_, e = arow - b * E_;
      size_t xbase = (size_t)(b * XROW + e) * 64;
      af[rt][0] = ld8b(x, xbase + q*8, f32);
      af[rt][1] = ld8b(x, xbase + 32 + q*8, f32);
    }
    f32x4 acc[2][4];
    #pragma unroll
    for (int rt = 0; rt < 2; ++rt)
      #pragma unroll
      for (int c = 0; c < 4; ++c) acc[rt][c] = (f32x4){0.f, 0.f, 0.f, 0.f};
    #pragma unroll
    for (int c = 0; c < 4; ++c) {
      short8 b0 = *reinterpret_cast<const short8*>(&Wte[(c*16 + m16)*64 + q*8]);
      short8 b1 = *reinterpret_cast<const short8*>(&Wte[(c*16 + m16)*64 + 32 + q*8]);
      #pragma unroll
      for (int rt = 0; rt < 2; ++rt) {
        acc[rt][c] = __builtin_amdgcn_mfma_f32_16x16x32_bf16(af[rt][0], b0, acc[rt][c], 0, 0, 0);
        acc[rt][c] = __builtin_amdgcn_mfma_f32_16x16x32_bf16(af[rt][1], b1, acc[rt][c], 0, 0, 0);
      }
    }
    #pragma unroll
    for (int rt = 0; rt < 2; ++rt)
      #pragma unroll
      for (int c = 0; c < 4; ++c) {
        int col = c*16 + m16;
        #pragma unroll
        for (int r = 0; r < 4; ++r) {
          int row = row0 + rt*16 + q*4 + r;
          fe[(size_t)row*64 + col] = __float2bfloat16(acc[rt][c][r]);
        }
      }
  }
}

// ---------- Kernel C: paired-edge gather+combine+lrelu+logit + softmax partial
// Block = 256 threads = 32 groups of 8 lanes; each group handles ONE undirected
// edge e=(u,v) -> BOTH directed rows p0 (u->v) and p1 (v->u):
//   row(p0) = hs[u]+fe[e]+hd[v], row(p1) = hs[v]+fe[e]+hd[u]
// 5 gathers per 2 rows (was 6) + one 16B epair load (was 6 scalar idx loads).
// hsd interleaved layout keeps hs[u]/hd[u] in the same 256B neighborhood.
// 4000 blocks (250/batch); XCD swizzle chunk = (bid&7)*500 + bid>>3.
__global__ __launch_bounds__(256) void k_combine(
    const int* __restrict__ flags,
    const bf16* __restrict__ hsd, const bf16* __restrict__ fe,
    const void* __restrict__ w_attn,
    const int4* __restrict__ epair,
    void* __restrict__ out, float* __restrict__ logits,
    float* __restrict__ mpart, float* __restrict__ spart) {
  const int f32 = flags[0];
  __shared__ float ld_log[64];
  int t = threadIdx.x;
  int chunk = (blockIdx.x & 7) * 500 + (blockIdx.x >> 3);  // bijective, 4000%8==0
  int lane = t & 63, wave = t >> 6;
  int grp = lane >> 3, sub = lane & 7, c0 = sub * 8;
  int gidx = wave * 8 + grp;                // [0,32) group in block
  int b = chunk / 250;
  int e = (chunk - b * 250) * 32 + gidx;    // undirected edge in [0, E_)
  int4 pr = epair[e];
  int u = pr.x, v2 = pr.y, p0 = pr.z, p1 = pr.w;
  const u16* hb = (const u16*)hsd + (size_t)b * N_ * 128;
  uint4 su = *reinterpret_cast<const uint4*>(hb + (size_t)u  * 128 + c0);       // hs[u]
  uint4 du = *reinterpret_cast<const uint4*>(hb + (size_t)u  * 128 + 64 + c0);  // hd[u]
  uint4 sv = *reinterpret_cast<const uint4*>(hb + (size_t)v2 * 128 + c0);       // hs[v]
  uint4 dv = *reinterpret_cast<const uint4*>(hb + (size_t)v2 * 128 + 64 + c0);  // hd[v]
  uint4 uf = *reinterpret_cast<const uint4*>((const u16*)fe + (size_t)(b*E_ + e)*64 + c0);
  float w[8];
  if (f32) {
    float4 w0 = *reinterpret_cast<const float4*>((const float*)w_attn + c0);
    float4 w1 = *reinterpret_cast<const float4*>((const float*)w_attn + c0 + 4);
    w[0] = w0.x; w[1] = w0.y; w[2] = w0.z; w[3] = w0.w;
    w[4] = w1.x; w[5] = w1.y; w[6] = w1.z; w[7] = w1.w;
  } else {
    uint4 uw = *reinterpret_cast<const uint4*>((const u16*)w_attn + c0);
    w[0] = lo2f(uw.x); w[1] = hi2f(uw.x);
    w[2] = lo2f(uw.y); w[3] = hi2f(uw.y);
    w[4] = lo2f(uw.z); w[5] = hi2f(uw.z);
    w[6] = lo2f(uw.w); w[7] = hi2f(uw.w);
  }
  float vA[8], vB[8];   // A: u->v (row p0) = hs_u+fe+hd_v ; B: v->u (row p1)
  vA[0] = lo2f(su.x) + lo2f(uf.x) + lo2f(dv.x);
  vA[1] = hi2f(su.x) + hi2f(uf.x) + hi2f(dv.x);
  vA[2] = lo2f(su.y) + lo2f(uf.y) + lo2f(dv.y);
  vA[3] = hi2f(su.y) + hi2f(uf.y) + hi2f(dv.y);
  vA[4] = lo2f(su.z) + lo2f(uf.z) + lo2f(dv.z);
  vA[5] = hi2f(su.z) + hi2f(uf.z) + hi2f(dv.z);
  vA[6] = lo2f(su.w) + lo2f(uf.w) + lo2f(dv.w);
  vA[7] = hi2f(su.w) + hi2f(uf.w) + hi2f(dv.w);
  vB[0] = lo2f(sv.x) + lo2f(uf.x) + lo2f(du.x);
  vB[1] = hi2f(sv.x) + hi2f(uf.x) + hi2f(du.x);
  vB[2] = lo2f(sv.y) + lo2f(uf.y) + lo2f(du.y);
  vB[3] = hi2f(sv.y) + hi2f(uf.y) + hi2f(du.y);
  vB[4] = lo2f(sv.z) + lo2f(uf.z) + lo2f(du.z);
  vB[5] = hi2f(sv.z) + hi2f(uf.z) + hi2f(du.z);
  vB[6] = lo2f(sv.w) + lo2f(uf.w) + lo2f(du.w);
  vB[7] = hi2f(sv.w) + hi2f(uf.w) + hi2f(du.w);
  float lA = 0.f, lB = 0.f;
  #pragma unroll
  for (int j = 0; j < 8; ++j) {
    vA[j] = vA[j] > 0.f ? vA[j] : 0.01f * vA[j];
    vB[j] = vB[j] > 0.f ? vB[j] : 0.01f * vB[j];
    lA += vA[j] * w[j];
    lB += vB[j] * w[j];
  }
  size_t ob0 = (size_t)(b*OROW + p0)*64 + c0;
  size_t ob1 = (size_t)(b*OROW + p1)*64 + c0;
  if (f32) {
    f32x4 a0; a0[0] = vA[0]; a0[1] = vA[1]; a0[2] = vA[2]; a0[3] = vA[3];
    f32x4 a1; a1[0] = vA[4]; a1[1] = vA[5]; a1[2] = vA[6]; a1[3] = vA[7];
    f32x4 b0; b0[0] = vB[0]; b0[1] = vB[1]; b0[2] = vB[2]; b0[3] = vB[3];
    f32x4 b1; b1[0] = vB[4]; b1[1] = vB[5]; b1[2] = vB[6]; b1[3] = vB[7];
    __builtin_nontemporal_store(a0, reinterpret_cast<f32x4*>((float*)out + ob0));
    __builtin_nontemporal_store(a1, reinterpret_cast<f32x4*>((float*)out + ob0 + 4));
    __builtin_nontemporal_store(b0, reinterpret_cast<f32x4*>((float*)out + ob1));
    __builtin_nontemporal_store(b1, reinterpret_cast<f32x4*>((float*)out + ob1 + 4));
  } else {
    u32x4 oa, ob;
    oa[0] = ((u32)f2bu(vA[1]) << 16) | f2bu(vA[0]);
    oa[1] = ((u32)f2bu(vA[3]) << 16) | f2bu(vA[2]);
    oa[2] = ((u32)f2bu(vA[5]) << 16) | f2bu(vA[4]);
    oa[3] = ((u32)f2bu(vA[7]) << 16) | f2bu(vA[6]);
    ob[0] = ((u32)f2bu(vB[1]) << 16) | f2bu(vB[0]);
    ob[1] = ((u32)f2bu(vB[3]) << 16) | f2bu(vB[2]);
    ob[2] = ((u32)f2bu(vB[5]) << 16) | f2bu(vB[4]);
    ob[3] = ((u32)f2bu(vB[7]) << 16) | f2bu(vB[6]);
    __builtin_nontemporal_store(oa, reinterpret_cast<u32x4*>((u16*)out + ob0));
    __builtin_nontemporal_store(ob, reinterpret_cast<u32x4*>((u16*)out + ob1));
  }
  lA += __shfl_down(lA, 4, 8);
  lA += __shfl_down(lA, 2, 8);
  lA += __shfl_down(lA, 1, 8);
  lB += __shfl_down(lB, 4, 8);
  lB += __shfl_down(lB, 2, 8);
  lB += __shfl_down(lB, 1, 8);
  if (sub == 0) {
    logits[b*P_ + p0] = lA;
    logits[b*P_ + p1] = lB;
    ld_log[gidx*2]     = lA;
    ld_log[gidx*2 + 1] = lB;
  }
  __syncthreads();
  if (t < 64) {
    float li = ld_log[t];
    float m = li;
    #pragma unroll
    for (int o = 32; o > 0; o >>= 1) m = fmaxf(m, __shfl_xor(m, o, 64));
    float sv2 = __expf(li - m);
    #pragma unroll
    for (int o = 32; o > 0; o >>= 1) sv2 += __shfl_xor(sv2, o, 64);
    if (t == 0) { mpart[chunk] = m; spart[chunk] = sv2; }
  }
}

// ---------- Kernel C2: merge 250 partials per batch -> (M, 1/S) ----------
__global__ __launch_bounds__(256) void k_smerge(
    const float* __restrict__ mpart, const float* __restrict__ spart,
    float* __restrict__ mb, float* __restrict__ sb) {
  __shared__ float rm[256], rs[256];
  int b = blockIdx.x, t = threadIdx.x;
  float m = -1e30f, s = 0.f;
  for (int j = t; j < 250; j += 256) {
    float mj = mpart[250*b + j], sj = spart[250*b + j];
    float nm = fmaxf(m, mj);
    s = s * __expf(m - nm) + sj * __expf(mj - nm);
    m = nm;
  }
  rm[t] = m; rs[t] = s; __syncthreads();
  for (int st = 128; st > 0; st >>= 1) {
    if (t < st) {
      float mo = rm[t + st], so = rs[t + st];
      float nm = fmaxf(rm[t], mo);
      rs[t] = rs[t] * __expf(rm[t] - nm) + so * __expf(mo - nm);
      rm[t] = nm;
    }
    __syncthreads();
  }
  if (t == 0) { mb[b] = rm[0]; sb[b] = 1.0f / rs[0]; }
}

// ---------- Kernel D: h_out ----------
// grid (N_, 4), block 256 = 4 waves (one batch each). rowptr gives the node's
// edge range; 4 edge-groups x 16 ch gather-dot; xor-reduce across groups.
__global__ __launch_bounds__(256) void k_hout(
    const int* __restrict__ flags,
    const bf16* __restrict__ h, const float* __restrict__ logits,
    const float* __restrict__ mb, const float* __restrict__ sb,
    const int* __restrict__ rowptr, const int* __restrict__ dst,
    void* __restrict__ out) {
  const int f32 = flags[0];
  int n = blockIdx.x;
  int t = threadIdx.x;
  int wave = t >> 6, lane = t & 63;
  int b = blockIdx.y * 4 + wave;
  float m = mb[b], inv = sb[b];
  int start = rowptr[n], end = rowptr[n + 1];
  int grp = lane >> 4, sub = lane & 15, c0 = sub * 4;
  float a0 = 0.f, a1 = 0.f, a2 = 0.f, a3 = 0.f;
  for (int p = start + grp; p < end; p += 4) {
    float a = __expf(logits[b*P_ + p] - m) * inv;
    int dn = dst[p];
    ushort4 hv = *reinterpret_cast<const ushort4*>((const u16*)h + (size_t)(b*N_ + dn)*64 + c0);
    a0 += a * u2f(hv.x); a1 += a * u2f(hv.y);
    a2 += a * u2f(hv.z); a3 += a * u2f(hv.w);
  }
  a0 += __shfl_xor(a0, 16, 64); a0 += __shfl_xor(a0, 32, 64);
  a1 += __shfl_xor(a1, 16, 64); a1 += __shfl_xor(a1, 32, 64);
  a2 += __shfl_xor(a2, 16, 64); a2 += __shfl_xor(a2, 32, 64);
  a3 += __shfl_xor(a3, 16, 64); a3 += __shfl_xor(a3, 32, 64);
  if (grp == 0) {
    size_t obase = (size_t)(b*OROW + P_ + n)*64 + c0;
    if (f32) {
      f32x4 o4; o4[0] = a0; o4[1] = a1; o4[2] = a2; o4[3] = a3;
      __builtin_nontemporal_store(o4, reinterpret_cast<f32x4*>((float*)out + obase));
    } else {
      u16x4 o4;
      o4[0] = f2bu(a0); o4[1] = f2bu(a1); o4[2] = f2bu(a2); o4[3] = f2bu(a3);
      __builtin_nontemporal_store(o4, reinterpret_cast<u16x4*>((u16*)out + obase));
    }
  }
}

extern "C" void kernel_launch(void* const* d_in, const int* in_sizes, int n_in,
                              void* d_out, int out_size, void* d_ws, size_t ws_size,
                              hipStream_t stream) {
  const void* x      = d_in[0];
  const void* W_edge = d_in[1];
  const void* W_node = d_in[2];
  const void* b_node = d_in[3];
  const void* W_comb = d_in[4];
  const void* b_comb = d_in[5];
  const void* w_attn = d_in[6];
  const int* src  = (const int*)d_in[7];
  const int* dst  = (const int*)d_in[8];
  const int* eidx = (const int*)d_in[9];

  // workspace layout (f32 units)
  float* logits = (float*)d_ws;          // 256000
  float* mpart  = logits + B_*P_;        // 4000
  float* spart  = mpart + 4000;          // 4000
  float* mb     = spart + 4000;          // 16
  float* sb     = mb + B_;               // 16
  float* c1     = sb + B_;               // 64
  float* c3     = c1 + 64;               // 64
  int*   rowptr = (int*)(c3 + 64);       // 2016 (padded)
  int*   flags  = rowptr + 2016;         // 16 (dtype flag, padded)
  int4*  epair  = (int4*)(flags + 16);   // 8000 x int4
  u16*   Wtn    = (u16*)(epair + E_);    // 192*64
  u16*   Wte    = Wtn + 192*64;          // 64*64
  bf16*  h      = (bf16*)(Wte + 64*64);  // B*N*64
  bf16*  hsd    = h + B_*N_*64;          // B*N*128 (interleaved [hs|hd])
  bf16*  fe     = hsd + B_*N_*128;       // B*E*64

  k_pre<<<135, 256, 0, stream>>>(x, W_edge, W_node, b_node, W_comb, b_comb, src, dst, eidx, Wtn, Wte, c1, c3, rowptr, flags, epair);
  k_transform<<<1500, 256, 0, stream>>>(x, flags, Wtn, Wte, b_node, c1, c3, h, hsd, fe);
  k_combine<<<4000, 256, 0, stream>>>(flags, hsd, fe, w_attn, epair, d_out, logits, mpart, spart);
  k_smerge<<<B_, 256, 0, stream>>>(mpart, spart, mb, sb);
  k_hout<<<dim3(N_, B_/4), 256, 0, stream>>>(flags, h, logits, mb, sb, rowptr, dst, d_out);
}

// Round 10
// 176.609 us; speedup vs baseline: 1.0788x; 1.0788x over previous
//
#include <hip/hip_runtime.h>
#include <hip/hip_bf16.h>

#define B_ 16
#define N_ 2000
#define E_ 8000
#define P_ 16000
#define XROW (E_ + N_)   // 10000 rows per batch in x
#define OROW (P_ + N_)   // 18000 rows per batch in out

typedef __hip_bfloat16 bf16;
typedef unsigned short u16;
typedef unsigned int u32;
typedef __attribute__((ext_vector_type(8))) short short8;   // 8 bf16 in 4 VGPRs
typedef __attribute__((ext_vector_type(4))) float f32x4;
typedef __attribute__((ext_vector_type(4))) unsigned int u32x4;    // nt-store-able
typedef __attribute__((ext_vector_type(4))) unsigned short u16x4;  // nt-store-able

__device__ __forceinline__ float b2f(bf16 v) { return __bfloat162float(v); }
__device__ __forceinline__ float u2f(u16 u) { return __uint_as_float(((u32)u) << 16); }
__device__ __forceinline__ float lo2f(u32 u) { return __uint_as_float(u << 16); }
__device__ __forceinline__ float hi2f(u32 u) { return __uint_as_float(u & 0xFFFF0000u); }
__device__ __forceinline__ u16 f2bu(float v) {
  bf16 b = __float2bfloat16(v);
  return *reinterpret_cast<u16*>(&b);
}

// dtype-agnostic input load
__device__ __forceinline__ float ldin(const void* p, int i, int f32) {
  return f32 ? ((const float*)p)[i] : __bfloat162float(((const bf16*)p)[i]);
}

// dtype self-detect: view first 512B of x as bf16; f32 data shows ~70%
// wild/non-finite values in the low halves. Run ONCE in k_pre (R5).
__device__ __forceinline__ int detect_f32(const void* x) {
  int lane = threadIdx.x & 63;
  ushort4 v = reinterpret_cast<const ushort4*>(x)[lane];
  int bad = 0;
  float f0 = u2f(v.x), f1 = u2f(v.y), f2 = u2f(v.z), f3 = u2f(v.w);
  if (!(fabsf(f0) < 1e4f)) bad++;
  if (!(fabsf(f1) < 1e4f)) bad++;
  if (!(fabsf(f2) < 1e4f)) bad++;
  if (!(fabsf(f3) < 1e4f)) bad++;
  unsigned long long m = __ballot(bad > 0);
  return __popcll(m) > 8;
}

// 8 consecutive input elems -> short8 of bf16 (A-fragment load)
__device__ __forceinline__ short8 ld8b(const void* p, size_t i, int f32) {
  short8 r;
  if (f32) {
    const float* f = (const float*)p + i;
    float4 v0 = *reinterpret_cast<const float4*>(f);
    float4 v1 = *reinterpret_cast<const float4*>(f + 4);
    u16* o = (u16*)&r;
    o[0] = f2bu(v0.x); o[1] = f2bu(v0.y); o[2] = f2bu(v0.z); o[3] = f2bu(v0.w);
    o[4] = f2bu(v1.x); o[5] = f2bu(v1.y); o[6] = f2bu(v1.z); o[7] = f2bu(v1.w);
  } else {
    r = *reinterpret_cast<const short8*>((const u16*)p + i);
  }
  return r;
}

// ---------- Kernel A: weight precompute (transposed bf16) + rowptr + flag ----
// Wtn[c][k] (192x64): c<64 -> W_node^T; c<128 -> (W_node@W1)^T; else (W_node@W3)^T
// Wte[c][k] (64x64): (W_edge@W2)^T.
// c1 = b_node@W1 + b_comb (bias fold -> hs carries the combine bias).
// c3 = b_node@W3.  rowptr[n] = lower_bound(src, n).  flags[0] = f32 dtype flag.
__global__ __launch_bounds__(256) void k_pre(
    const void* __restrict__ x,
    const void* __restrict__ W_edge, const void* __restrict__ W_node,
    const void* __restrict__ b_node, const void* __restrict__ W_comb,
    const void* __restrict__ b_comb,
    const int* __restrict__ src,
    u16* __restrict__ Wtn, u16* __restrict__ Wte,
    float* __restrict__ c1, float* __restrict__ c3,
    int* __restrict__ rowptr, int* __restrict__ flags) {
  const int f32 = detect_f32(x);
  int o = blockIdx.x * 256 + threadIdx.x;
  if (o < 4096) {
    int c = o >> 6, k = o & 63;
    Wtn[c*64 + k] = f2bu(ldin(W_node, k*64 + c, f32));
  } else if (o < 12288) {
    int oo = o - 4096;            // [0, 8192)
    int cc = oo >> 6, k = oo & 63;
    int col = cc & 63;
    int base = (cc < 64) ? 0 : 128;
    float a = 0.f;
    for (int j = 0; j < 64; ++j)
      a += ldin(W_node, k*64 + j, f32) * ldin(W_comb, (base + j)*64 + col, f32);
    Wtn[(64 + cc)*64 + k] = f2bu(a);
  } else if (o < 16384) {
    int oo = o - 12288;
    int c = oo >> 6, k = oo & 63;
    float a = 0.f;
    for (int j = 0; j < 64; ++j)
      a += ldin(W_edge, k*64 + j, f32) * ldin(W_comb, (64 + j)*64 + c, f32);
    Wte[c*64 + k] = f2bu(a);
  } else if (o < 16448) {
    int j = o - 16384;
    float a = ldin(b_comb, j, f32);               // b_comb fold
    for (int k = 0; k < 64; ++k) a += ldin(b_node, k, f32) * ldin(W_comb, k*64 + j, f32);
    c1[j] = a;
  } else if (o < 16512) {
    int j = o - 16448;
    float a = 0.f;
    for (int k = 0; k < 64; ++k) a += ldin(b_node, k, f32) * ldin(W_comb, (128 + k)*64 + j, f32);
    c3[j] = a;
  } else if (o < 16512 + N_ + 1) {
    int n = o - 16512;
    int lo = 0, hi = P_;
    while (lo < hi) { int mid = (lo + hi) >> 1; if (src[mid] < n) lo = mid + 1; else hi = mid; }
    rowptr[n] = lo;
  } else if (o == 16512 + N_ + 1) {
    flags[0] = f32;
  }
}

// ---------- Kernel B: fused node+edge transform, MFMA, LDS-free ----------
// blocks [0,500): node rows, 64/block (4 waves x 16 rows), 12 col-tiles:
//   [h|hs|hd](64x192) = X @ Wn(64x192)
// blocks [500,1500): edge rows, 128/block (4 waves x 32 rows), 4 col-tiles:
//   fe(128x64) = X @ A2
__global__ __launch_bounds__(256) void k_transform(
    const void* __restrict__ x, const int* __restrict__ flags,
    const u16* __restrict__ Wtn, const u16* __restrict__ Wte,
    const void* __restrict__ b_node,
    const float* __restrict__ c1, const float* __restrict__ c3,
    bf16* __restrict__ h, bf16* __restrict__ hs, bf16* __restrict__ hd,
    bf16* __restrict__ fe) {
  const int f32 = flags[0];
  int t = threadIdx.x;
  int wave = t >> 6, lane = t & 63;
  int m16 = lane & 15, q = lane >> 4;
  if (blockIdx.x < 500) {
    int row0 = blockIdx.x * 64 + wave * 16;
    int arow = row0 + m16;
    int b = arow / N_, n = arow - b * N_;
    size_t xbase = (size_t)(b * XROW + E_ + n) * 64;
    short8 af0 = ld8b(x, xbase + q*8, f32);
    short8 af1 = ld8b(x, xbase + 32 + q*8, f32);
    f32x4 acc[12];
    #pragma unroll
    for (int c = 0; c < 12; ++c) acc[c] = (f32x4){0.f, 0.f, 0.f, 0.f};
    #pragma unroll
    for (int c = 0; c < 12; ++c) {
      short8 b0 = *reinterpret_cast<const short8*>(&Wtn[(c*16 + m16)*64 + q*8]);
      short8 b1 = *reinterpret_cast<const short8*>(&Wtn[(c*16 + m16)*64 + 32 + q*8]);
      acc[c] = __builtin_amdgcn_mfma_f32_16x16x32_bf16(af0, b0, acc[c], 0, 0, 0);
      acc[c] = __builtin_amdgcn_mfma_f32_16x16x32_bf16(af1, b1, acc[c], 0, 0, 0);
    }
    // D: col = m16 (within tile), row = q*4 + r
    #pragma unroll
    for (int c = 0; c < 12; ++c) {
      int seg = c >> 2;             // 0:h 1:hs 2:hd
      int lcol = (c*16 + m16) & 63;
      float bias = (seg == 0) ? ldin(b_node, lcol, f32) : (seg == 1 ? c1[lcol] : c3[lcol]);
      bf16* tgt = (seg == 0) ? h : (seg == 1 ? hs : hd);
      #pragma unroll
      for (int r = 0; r < 4; ++r) {
        int row = row0 + q*4 + r;
        tgt[(size_t)row*64 + lcol] = __float2bfloat16(acc[c][r] + bias);
      }
    }
  } else {
    int row0 = (blockIdx.x - 500) * 128 + wave * 32;
    short8 af[2][2];
    #pragma unroll
    for (int rt = 0; rt < 2; ++rt) {
      int arow = row0 + rt*16 + m16;
      int b = arow / E_, e = arow - b * E_;
      size_t xbase = (size_t)(b * XROW + e) * 64;
      af[rt][0] = ld8b(x, xbase + q*8, f32);
      af[rt][1] = ld8b(x, xbase + 32 + q*8, f32);
    }
    f32x4 acc[2][4];
    #pragma unroll
    for (int rt = 0; rt < 2; ++rt)
      #pragma unroll
      for (int c = 0; c < 4; ++c) acc[rt][c] = (f32x4){0.f, 0.f, 0.f, 0.f};
    #pragma unroll
    for (int c = 0; c < 4; ++c) {
      short8 b0 = *reinterpret_cast<const short8*>(&Wte[(c*16 + m16)*64 + q*8]);
      short8 b1 = *reinterpret_cast<const short8*>(&Wte[(c*16 + m16)*64 + 32 + q*8]);
      #pragma unroll
      for (int rt = 0; rt < 2; ++rt) {
        acc[rt][c] = __builtin_amdgcn_mfma_f32_16x16x32_bf16(af[rt][0], b0, acc[rt][c], 0, 0, 0);
        acc[rt][c] = __builtin_amdgcn_mfma_f32_16x16x32_bf16(af[rt][1], b1, acc[rt][c], 0, 0, 0);
      }
    }
    #pragma unroll
    for (int rt = 0; rt < 2; ++rt)
      #pragma unroll
      for (int c = 0; c < 4; ++c) {
        int col = c*16 + m16;
        #pragma unroll
        for (int r = 0; r < 4; ++r) {
          int row = row0 + rt*16 + q*4 + r;
          fe[(size_t)row*64 + col] = __float2bfloat16(acc[rt][c][r]);
        }
      }
  }
}

// ---------- Kernel C: gather+combine+lrelu+logit + per-block softmax partial --
// 64 rows/block (R10: was 32) = 32 groups of 8 lanes x 2 rows each (r0, r0+32)
// -> 4000 blocks, halved prologue/softmax-partial overhead, 2 rows in flight
// per group (better MLP), and out-store runs stay fully coalesced (consecutive
// rows per block — the R9 lesson). All 64 rows same batch (16000/64 = 250).
// XCD swizzle chunk = (bid&7)*500 + bid>>3; mpart/spart indexed by CHUNK
// (batch b partials = chunks [250b, 250b+250), matching k_smerge).
__global__ __launch_bounds__(256) void k_combine(
    const int* __restrict__ flags,
    const bf16* __restrict__ hs, const bf16* __restrict__ hd,
    const bf16* __restrict__ fe,
    const void* __restrict__ w_attn,
    const int* __restrict__ src, const int* __restrict__ dst,
    const int* __restrict__ eidx,
    void* __restrict__ out, float* __restrict__ logits,
    float* __restrict__ mpart, float* __restrict__ spart) {
  const int f32 = flags[0];
  __shared__ float ld_log[64];
  int t = threadIdx.x;
  int chunk = (blockIdx.x & 7) * 500 + (blockIdx.x >> 3);  // bijective, 4000%8==0
  int lane = t & 63, wave = t >> 6;
  int grp = lane >> 3, sub = lane & 7, c0 = sub * 8;
  int gidx = wave * 8 + grp;               // [0,32)
  int r0 = chunk * 64 + gidx;              // first row of this group
  int b = r0 / P_;
  int p0 = r0 - b * P_, p1 = p0 + 32;
  int s0 = src[p0], d0 = dst[p0], e0 = eidx[p0];
  int s1 = src[p1], d1 = dst[p1], e1 = eidx[p1];
  const u16* hsb = (const u16*)hs + (size_t)b * N_ * 64;
  const u16* hdb = (const u16*)hd + (size_t)b * N_ * 64;
  const u16* feb = (const u16*)fe + (size_t)b * E_ * 64;
  uint4 ua0 = *reinterpret_cast<const uint4*>(hsb + (size_t)s0*64 + c0);
  uint4 uf0 = *reinterpret_cast<const uint4*>(feb + (size_t)e0*64 + c0);
  uint4 ud0 = *reinterpret_cast<const uint4*>(hdb + (size_t)d0*64 + c0);
  uint4 ua1 = *reinterpret_cast<const uint4*>(hsb + (size_t)s1*64 + c0);
  uint4 uf1 = *reinterpret_cast<const uint4*>(feb + (size_t)e1*64 + c0);
  uint4 ud1 = *reinterpret_cast<const uint4*>(hdb + (size_t)d1*64 + c0);
  float w[8];
  if (f32) {
    float4 w0 = *reinterpret_cast<const float4*>((const float*)w_attn + c0);
    float4 w1 = *reinterpret_cast<const float4*>((const float*)w_attn + c0 + 4);
    w[0] = w0.x; w[1] = w0.y; w[2] = w0.z; w[3] = w0.w;
    w[4] = w1.x; w[5] = w1.y; w[6] = w1.z; w[7] = w1.w;
  } else {
    uint4 uw = *reinterpret_cast<const uint4*>((const u16*)w_attn + c0);
    w[0] = lo2f(uw.x); w[1] = hi2f(uw.x);
    w[2] = lo2f(uw.y); w[3] = hi2f(uw.y);
    w[4] = lo2f(uw.z); w[5] = hi2f(uw.z);
    w[6] = lo2f(uw.w); w[7] = hi2f(uw.w);
  }
  float vA[8], vB[8];
  vA[0] = lo2f(ua0.x) + lo2f(uf0.x) + lo2f(ud0.x);
  vA[1] = hi2f(ua0.x) + hi2f(uf0.x) + hi2f(ud0.x);
  vA[2] = lo2f(ua0.y) + lo2f(uf0.y) + lo2f(ud0.y);
  vA[3] = hi2f(ua0.y) + hi2f(uf0.y) + hi2f(ud0.y);
  vA[4] = lo2f(ua0.z) + lo2f(uf0.z) + lo2f(ud0.z);
  vA[5] = hi2f(ua0.z) + hi2f(uf0.z) + hi2f(ud0.z);
  vA[6] = lo2f(ua0.w) + lo2f(uf0.w) + lo2f(ud0.w);
  vA[7] = hi2f(ua0.w) + hi2f(uf0.w) + hi2f(ud0.w);
  vB[0] = lo2f(ua1.x) + lo2f(uf1.x) + lo2f(ud1.x);
  vB[1] = hi2f(ua1.x) + hi2f(uf1.x) + hi2f(ud1.x);
  vB[2] = lo2f(ua1.y) + lo2f(uf1.y) + lo2f(ud1.y);
  vB[3] = hi2f(ua1.y) + hi2f(uf1.y) + hi2f(ud1.y);
  vB[4] = lo2f(ua1.z) + lo2f(uf1.z) + lo2f(ud1.z);
  vB[5] = hi2f(ua1.z) + hi2f(uf1.z) + hi2f(ud1.z);
  vB[6] = lo2f(ua1.w) + lo2f(uf1.w) + lo2f(ud1.w);
  vB[7] = hi2f(ua1.w) + hi2f(uf1.w) + hi2f(ud1.w);
  float lA = 0.f, lB = 0.f;
  #pragma unroll
  for (int j = 0; j < 8; ++j) {
    vA[j] = vA[j] > 0.f ? vA[j] : 0.01f * vA[j];
    vB[j] = vB[j] > 0.f ? vB[j] : 0.01f * vB[j];
    lA += vA[j] * w[j];
    lB += vB[j] * w[j];
  }
  size_t ob0 = (size_t)(b*OROW + p0)*64 + c0;
  size_t ob1 = (size_t)(b*OROW + p1)*64 + c0;
  if (f32) {
    f32x4 a0; a0[0] = vA[0]; a0[1] = vA[1]; a0[2] = vA[2]; a0[3] = vA[3];
    f32x4 a1; a1[0] = vA[4]; a1[1] = vA[5]; a1[2] = vA[6]; a1[3] = vA[7];
    f32x4 b0; b0[0] = vB[0]; b0[1] = vB[1]; b0[2] = vB[2]; b0[3] = vB[3];
    f32x4 b1; b1[0] = vB[4]; b1[1] = vB[5]; b1[2] = vB[6]; b1[3] = vB[7];
    __builtin_nontemporal_store(a0, reinterpret_cast<f32x4*>((float*)out + ob0));
    __builtin_nontemporal_store(a1, reinterpret_cast<f32x4*>((float*)out + ob0 + 4));
    __builtin_nontemporal_store(b0, reinterpret_cast<f32x4*>((float*)out + ob1));
    __builtin_nontemporal_store(b1, reinterpret_cast<f32x4*>((float*)out + ob1 + 4));
  } else {
    u32x4 oa, ob;
    oa[0] = ((u32)f2bu(vA[1]) << 16) | f2bu(vA[0]);
    oa[1] = ((u32)f2bu(vA[3]) << 16) | f2bu(vA[2]);
    oa[2] = ((u32)f2bu(vA[5]) << 16) | f2bu(vA[4]);
    oa[3] = ((u32)f2bu(vA[7]) << 16) | f2bu(vA[6]);
    ob[0] = ((u32)f2bu(vB[1]) << 16) | f2bu(vB[0]);
    ob[1] = ((u32)f2bu(vB[3]) << 16) | f2bu(vB[2]);
    ob[2] = ((u32)f2bu(vB[5]) << 16) | f2bu(vB[4]);
    ob[3] = ((u32)f2bu(vB[7]) << 16) | f2bu(vB[6]);
    __builtin_nontemporal_store(oa, reinterpret_cast<u32x4*>((u16*)out + ob0));
    __builtin_nontemporal_store(ob, reinterpret_cast<u32x4*>((u16*)out + ob1));
  }
  lA += __shfl_down(lA, 4, 8);
  lA += __shfl_down(lA, 2, 8);
  lA += __shfl_down(lA, 1, 8);
  lB += __shfl_down(lB, 4, 8);
  lB += __shfl_down(lB, 2, 8);
  lB += __shfl_down(lB, 1, 8);
  if (sub == 0) {
    logits[b*P_ + p0] = lA;
    logits[b*P_ + p1] = lB;
    ld_log[gidx]      = lA;
    ld_log[gidx + 32] = lB;
  }
  __syncthreads();
  if (t < 64) {
    float li = ld_log[t];
    float m = li;
    #pragma unroll
    for (int o = 32; o > 0; o >>= 1) m = fmaxf(m, __shfl_xor(m, o, 64));
    float sv = __expf(li - m);
    #pragma unroll
    for (int o = 32; o > 0; o >>= 1) sv += __shfl_xor(sv, o, 64);
    if (t == 0) { mpart[chunk] = m; spart[chunk] = sv; }
  }
}

// ---------- Kernel C2: merge 250 partials per batch -> (M, 1/S) ----------
__global__ __launch_bounds__(256) void k_smerge(
    const float* __restrict__ mpart, const float* __restrict__ spart,
    float* __restrict__ mb, float* __restrict__ sb) {
  __shared__ float rm[256], rs[256];
  int b = blockIdx.x, t = threadIdx.x;
  float m = -1e30f, s = 0.f;
  for (int j = t; j < 250; j += 256) {
    float mj = mpart[250*b + j], sj = spart[250*b + j];
    float nm = fmaxf(m, mj);
    s = s * __expf(m - nm) + sj * __expf(mj - nm);
    m = nm;
  }
  rm[t] = m; rs[t] = s; __syncthreads();
  for (int st = 128; st > 0; st >>= 1) {
    if (t < st) {
      float mo = rm[t + st], so = rs[t + st];
      float nm = fmaxf(rm[t], mo);
      rs[t] = rs[t] * __expf(rm[t] - nm) + so * __expf(mo - nm);
      rm[t] = nm;
    }
    __syncthreads();
  }
  if (t == 0) { mb[b] = rm[0]; sb[b] = 1.0f / rs[0]; }
}

// ---------- Kernel D: h_out ----------
// grid (N_, 4), block 256 = 4 waves (one batch each). rowptr gives the node's
// edge range; 4 edge-groups x 16 ch gather-dot; xor-reduce across groups.
__global__ __launch_bounds__(256) void k_hout(
    const int* __restrict__ flags,
    const bf16* __restrict__ h, const float* __restrict__ logits,
    const float* __restrict__ mb, const float* __restrict__ sb,
    const int* __restrict__ rowptr, const int* __restrict__ dst,
    void* __restrict__ out) {
  const int f32 = flags[0];
  int n = blockIdx.x;
  int t = threadIdx.x;
  int wave = t >> 6, lane = t & 63;
  int b = blockIdx.y * 4 + wave;
  float m = mb[b], inv = sb[b];
  int start = rowptr[n], end = rowptr[n + 1];
  int grp = lane >> 4, sub = lane & 15, c0 = sub * 4;
  float a0 = 0.f, a1 = 0.f, a2 = 0.f, a3 = 0.f;
  for (int p = start + grp; p < end; p += 4) {
    float a = __expf(logits[b*P_ + p] - m) * inv;
    int dn = dst[p];
    ushort4 hv = *reinterpret_cast<const ushort4*>((const u16*)h + (size_t)(b*N_ + dn)*64 + c0);
    a0 += a * u2f(hv.x); a1 += a * u2f(hv.y);
    a2 += a * u2f(hv.z); a3 += a * u2f(hv.w);
  }
  a0 += __shfl_xor(a0, 16, 64); a0 += __shfl_xor(a0, 32, 64);
  a1 += __shfl_xor(a1, 16, 64); a1 += __shfl_xor(a1, 32, 64);
  a2 += __shfl_xor(a2, 16, 64); a2 += __shfl_xor(a2, 32, 64);
  a3 += __shfl_xor(a3, 16, 64); a3 += __shfl_xor(a3, 32, 64);
  if (grp == 0) {
    size_t obase = (size_t)(b*OROW + P_ + n)*64 + c0;
    if (f32) {
      f32x4 o4; o4[0] = a0; o4[1] = a1; o4[2] = a2; o4[3] = a3;
      __builtin_nontemporal_store(o4, reinterpret_cast<f32x4*>((float*)out + obase));
    } else {
      u16x4 o4;
      o4[0] = f2bu(a0); o4[1] = f2bu(a1); o4[2] = f2bu(a2); o4[3] = f2bu(a3);
      __builtin_nontemporal_store(o4, reinterpret_cast<u16x4*>((u16*)out + obase));
    }
  }
}

extern "C" void kernel_launch(void* const* d_in, const int* in_sizes, int n_in,
                              void* d_out, int out_size, void* d_ws, size_t ws_size,
                              hipStream_t stream) {
  const void* x      = d_in[0];
  const void* W_edge = d_in[1];
  const void* W_node = d_in[2];
  const void* b_node = d_in[3];
  const void* W_comb = d_in[4];
  const void* b_comb = d_in[5];
  const void* w_attn = d_in[6];
  const int* src  = (const int*)d_in[7];
  const int* dst  = (const int*)d_in[8];
  const int* eidx = (const int*)d_in[9];

  // workspace layout (f32 units)
  float* logits = (float*)d_ws;          // 256000
  float* mpart  = logits + B_*P_;        // 4000
  float* spart  = mpart + 4000;          // 4000
  float* mb     = spart + 4000;          // 16
  float* sb     = mb + B_;               // 16
  float* c1     = sb + B_;               // 64
  float* c3     = c1 + 64;               // 64
  int*   rowptr = (int*)(c3 + 64);       // 2016 (padded)
  int*   flags  = rowptr + 2016;         // 16 (dtype flag, padded)
  u16*   Wtn    = (u16*)(flags + 16);    // 192*64
  u16*   Wte    = Wtn + 192*64;          // 64*64
  bf16*  h      = (bf16*)(Wte + 64*64);  // B*N*64
  bf16*  hs     = h  + B_*N_*64;
  bf16*  hd     = hs + B_*N_*64;
  bf16*  fe     = hd + B_*N_*64;         // B*E*64

  k_pre<<<73, 256, 0, stream>>>(x, W_edge, W_node, b_node, W_comb, b_comb, src, Wtn, Wte, c1, c3, rowptr, flags);
  k_transform<<<1500, 256, 0, stream>>>(x, flags, Wtn, Wte, b_node, c1, c3, h, hs, hd, fe);
  k_combine<<<4000, 256, 0, stream>>>(flags, hs, hd, fe, w_attn, src, dst, eidx, d_out, logits, mpart, spart);
  k_smerge<<<B_, 256, 0, stream>>>(mpart, spart, mb, sb);
  k_hout<<<dim3(N_, B_/4), 256, 0, stream>>>(flags, h, logits, mb, sb, rowptr, dst, d_out);
}

// Round 11
// 176.070 us; speedup vs baseline: 1.0821x; 1.0031x over previous
//
#include <hip/hip_runtime.h>
#include <hip/hip_bf16.h>

#define B_ 16
#define N_ 2000
#define E_ 8000
#define P_ 16000
#define XROW (E_ + N_)   // 10000 rows per batch in x
#define OROW (P_ + N_)   // 18000 rows per batch in out

typedef __hip_bfloat16 bf16;
typedef unsigned short u16;
typedef unsigned int u32;
typedef __attribute__((ext_vector_type(8))) short short8;   // 8 bf16 in 4 VGPRs
typedef __attribute__((ext_vector_type(4))) float f32x4;
typedef __attribute__((ext_vector_type(4))) unsigned int u32x4;    // nt-store-able
typedef __attribute__((ext_vector_type(4))) unsigned short u16x4;  // nt-store-able

__device__ __forceinline__ float b2f(bf16 v) { return __bfloat162float(v); }
__device__ __forceinline__ float u2f(u16 u) { return __uint_as_float(((u32)u) << 16); }
__device__ __forceinline__ float lo2f(u32 u) { return __uint_as_float(u << 16); }
__device__ __forceinline__ float hi2f(u32 u) { return __uint_as_float(u & 0xFFFF0000u); }
__device__ __forceinline__ u16 f2bu(float v) {
  bf16 b = __float2bfloat16(v);
  return *reinterpret_cast<u16*>(&b);
}

// dtype-agnostic input load
__device__ __forceinline__ float ldin(const void* p, int i, int f32) {
  return f32 ? ((const float*)p)[i] : __bfloat162float(((const bf16*)p)[i]);
}

// dtype self-detect: view first 512B of x as bf16; f32 data shows ~70%
// wild/non-finite values in the low halves. Run ONCE in k_pre (R5: hoisting
// out of the per-block prologue was worth ~1.4 µs).
__device__ __forceinline__ int detect_f32(const void* x) {
  int lane = threadIdx.x & 63;
  ushort4 v = reinterpret_cast<const ushort4*>(x)[lane];
  int bad = 0;
  float f0 = u2f(v.x), f1 = u2f(v.y), f2 = u2f(v.z), f3 = u2f(v.w);
  if (!(fabsf(f0) < 1e4f)) bad++;
  if (!(fabsf(f1) < 1e4f)) bad++;
  if (!(fabsf(f2) < 1e4f)) bad++;
  if (!(fabsf(f3) < 1e4f)) bad++;
  unsigned long long m = __ballot(bad > 0);
  return __popcll(m) > 8;
}

// 8 consecutive input elems -> short8 of bf16 (A-fragment load)
__device__ __forceinline__ short8 ld8b(const void* p, size_t i, int f32) {
  short8 r;
  if (f32) {
    const float* f = (const float*)p + i;
    float4 v0 = *reinterpret_cast<const float4*>(f);
    float4 v1 = *reinterpret_cast<const float4*>(f + 4);
    u16* o = (u16*)&r;
    o[0] = f2bu(v0.x); o[1] = f2bu(v0.y); o[2] = f2bu(v0.z); o[3] = f2bu(v0.w);
    o[4] = f2bu(v1.x); o[5] = f2bu(v1.y); o[6] = f2bu(v1.z); o[7] = f2bu(v1.w);
  } else {
    r = *reinterpret_cast<const short8*>((const u16*)p + i);
  }
  return r;
}

// ---------- Kernel A: weight precompute (transposed bf16) + rowptr + flag ----
// Wtn[c][k] (192x64): c<64 -> W_node^T; c<128 -> (W_node@W1)^T; else (W_node@W3)^T
// Wte[c][k] (64x64): (W_edge@W2)^T.
// c1 = b_node@W1 + b_comb  (combine bias FOLDED here -> hs carries it, so
// k_combine needs no bias stage at all).  c3 = b_node@W3.
// rowptr[n] = lower_bound(src, n), n in [0,2000].  flags[0] = f32 dtype flag.
__global__ __launch_bounds__(256) void k_pre(
    const void* __restrict__ x,
    const void* __restrict__ W_edge, const void* __restrict__ W_node,
    const void* __restrict__ b_node, const void* __restrict__ W_comb,
    const void* __restrict__ b_comb,
    const int* __restrict__ src,
    u16* __restrict__ Wtn, u16* __restrict__ Wte,
    float* __restrict__ c1, float* __restrict__ c3,
    int* __restrict__ rowptr, int* __restrict__ flags) {
  const int f32 = detect_f32(x);
  int o = blockIdx.x * 256 + threadIdx.x;
  if (o < 4096) {
    int c = o >> 6, k = o & 63;
    Wtn[c*64 + k] = f2bu(ldin(W_node, k*64 + c, f32));
  } else if (o < 12288) {
    int oo = o - 4096;            // [0, 8192)
    int cc = oo >> 6, k = oo & 63;
    int col = cc & 63;
    int base = (cc < 64) ? 0 : 128;
    float a = 0.f;
    for (int j = 0; j < 64; ++j)
      a += ldin(W_node, k*64 + j, f32) * ldin(W_comb, (base + j)*64 + col, f32);
    Wtn[(64 + cc)*64 + k] = f2bu(a);
  } else if (o < 16384) {
    int oo = o - 12288;
    int c = oo >> 6, k = oo & 63;
    float a = 0.f;
    for (int j = 0; j < 64; ++j)
      a += ldin(W_edge, k*64 + j, f32) * ldin(W_comb, (64 + j)*64 + c, f32);
    Wte[c*64 + k] = f2bu(a);
  } else if (o < 16448) {
    int j = o - 16384;
    float a = ldin(b_comb, j, f32);               // b_comb fold
    for (int k = 0; k < 64; ++k) a += ldin(b_node, k, f32) * ldin(W_comb, k*64 + j, f32);
    c1[j] = a;
  } else if (o < 16512) {
    int j = o - 16448;
    float a = 0.f;
    for (int k = 0; k < 64; ++k) a += ldin(b_node, k, f32) * ldin(W_comb, (128 + k)*64 + j, f32);
    c3[j] = a;
  } else if (o < 16512 + N_ + 1) {
    int n = o - 16512;
    int lo = 0, hi = P_;
    while (lo < hi) { int mid = (lo + hi) >> 1; if (src[mid] < n) lo = mid + 1; else hi = mid; }
    rowptr[n] = lo;
  } else if (o == 16512 + N_ + 1) {
    flags[0] = f32;
  }
}

// ---------- Kernel B: fused node+edge transform, MFMA, LDS-free ----------
// blocks [0,500): node rows, 64/block (4 waves x 16 rows), 12 col-tiles:
//   [h|hs|hd](64x192) = X @ Wn(64x192)
// blocks [500,1500): edge rows, 128/block (4 waves x 32 rows), 4 col-tiles:
//   fe(128x64) = X @ A2
// A-frags straight from global x (coalesced: lanes {m,m+16,m+32,m+48} cover one
// row's 128B half); B-frags from precomputed transposed weights (L1-resident).
__global__ __launch_bounds__(256) void k_transform(
    const void* __restrict__ x, const int* __restrict__ flags,
    const u16* __restrict__ Wtn, const u16* __restrict__ Wte,
    const void* __restrict__ b_node,
    const float* __restrict__ c1, const float* __restrict__ c3,
    bf16* __restrict__ h, bf16* __restrict__ hs, bf16* __restrict__ hd,
    bf16* __restrict__ fe) {
  const int f32 = flags[0];
  int t = threadIdx.x;
  int wave = t >> 6, lane = t & 63;
  int m16 = lane & 15, q = lane >> 4;
  if (blockIdx.x < 500) {
    int row0 = blockIdx.x * 64 + wave * 16;
    int arow = row0 + m16;
    int b = arow / N_, n = arow - b * N_;
    size_t xbase = (size_t)(b * XROW + E_ + n) * 64;
    short8 af0 = ld8b(x, xbase + q*8, f32);
    short8 af1 = ld8b(x, xbase + 32 + q*8, f32);
    f32x4 acc[12];
    #pragma unroll
    for (int c = 0; c < 12; ++c) acc[c] = (f32x4){0.f, 0.f, 0.f, 0.f};
    #pragma unroll
    for (int c = 0; c < 12; ++c) {
      short8 b0 = *reinterpret_cast<const short8*>(&Wtn[(c*16 + m16)*64 + q*8]);
      short8 b1 = *reinterpret_cast<const short8*>(&Wtn[(c*16 + m16)*64 + 32 + q*8]);
      acc[c] = __builtin_amdgcn_mfma_f32_16x16x32_bf16(af0, b0, acc[c], 0, 0, 0);
      acc[c] = __builtin_amdgcn_mfma_f32_16x16x32_bf16(af1, b1, acc[c], 0, 0, 0);
    }
    // D: col = m16 (within tile), row = q*4 + r
    #pragma unroll
    for (int c = 0; c < 12; ++c) {
      int seg = c >> 2;             // 0:h 1:hs 2:hd
      int lcol = (c*16 + m16) & 63;
      float bias = (seg == 0) ? ldin(b_node, lcol, f32) : (seg == 1 ? c1[lcol] : c3[lcol]);
      bf16* tgt = (seg == 0) ? h : (seg == 1 ? hs : hd);
      #pragma unroll
      for (int r = 0; r < 4; ++r) {
        int row = row0 + q*4 + r;
        tgt[(size_t)row*64 + lcol] = __float2bfloat16(acc[c][r] + bias);
      }
    }
  } else {
    int row0 = (blockIdx.x - 500) * 128 + wave * 32;
    short8 af[2][2];
    #pragma unroll
    for (int rt = 0; rt < 2; ++rt) {
      int arow = row0 + rt*16 + m16;
      int b = arow / E_, e = arow - b * E_;
      size_t xbase = (size_t)(b * XROW + e) * 64;
      af[rt][0] = ld8b(x, xbase + q*8, f32);
      af[rt][1] = ld8b(x, xbase + 32 + q*8, f32);
    }
    f32x4 acc[2][4];
    #pragma unroll
    for (int rt = 0; rt < 2; ++rt)
      #pragma unroll
      for (int c = 0; c < 4; ++c) acc[rt][c] = (f32x4){0.f, 0.f, 0.f, 0.f};
    #pragma unroll
    for (int c = 0; c < 4; ++c) {
      short8 b0 = *reinterpret_cast<const short8*>(&Wte[(c*16 + m16)*64 + q*8]);
      short8 b1 = *reinterpret_cast<const short8*>(&Wte[(c*16 + m16)*64 + 32 + q*8]);
      #pragma unroll
      for (int rt = 0; rt < 2; ++rt) {
        acc[rt][c] = __builtin_amdgcn_mfma_f32_16x16x32_bf16(af[rt][0], b0, acc[rt][c], 0, 0, 0);
        acc[rt][c] = __builtin_amdgcn_mfma_f32_16x16x32_bf16(af[rt][1], b1, acc[rt][c], 0, 0, 0);
      }
    }
    #pragma unroll
    for (int rt = 0; rt < 2; ++rt)
      #pragma unroll
      for (int c = 0; c < 4; ++c) {
        int col = c*16 + m16;
        #pragma unroll
        for (int r = 0; r < 4; ++r) {
          int row = row0 + rt*16 + q*4 + r;
          fe[(size_t)row*64 + col] = __float2bfloat16(acc[rt][c][r]);
        }
      }
  }
}

// ---------- Kernel C: gather+combine+lrelu+logit + per-block softmax partial --
// 8 lanes/row x 8 ch (uint4 = 16B gathers), 32 rows/block (all same batch).
// XCD-chunk swizzle (T1): chunk = (bid&7)*1000 + bid>>3. mpart/spart indexed by
// CHUNK (batch b partials = chunks [500b, 500b+500), matching k_smerge).
// R8 slim-down: no bias stage (folded into hs via c1), no head LDS/barrier
// (w_attn read per-lane from global, L1-broadcast), indices loaded first so
// gathers issue at block start, nontemporal out stores (keep L2 for gathers).
__global__ __launch_bounds__(256) void k_combine(
    const int* __restrict__ flags,
    const bf16* __restrict__ hs, const bf16* __restrict__ hd,
    const bf16* __restrict__ fe,
    const void* __restrict__ w_attn,
    const int* __restrict__ src, const int* __restrict__ dst,
    const int* __restrict__ eidx,
    void* __restrict__ out, float* __restrict__ logits,
    float* __restrict__ mpart, float* __restrict__ spart) {
  const int f32 = flags[0];
  __shared__ float ld_log[32];
  int t = threadIdx.x;
  int chunk = (blockIdx.x & 7) * 1000 + (blockIdx.x >> 3);  // bijective, 8000%8==0
  int lane = t & 63, wave = t >> 6;
  int grp = lane >> 3, sub = lane & 7, c0 = sub * 8;
  int r = chunk * 32 + wave * 8 + grp;   // [0, B*P)
  int b = r / P_, p = r - b * P_;
  int s = src[p], d2 = dst[p], e = eidx[p];
  uint4 ua = *reinterpret_cast<const uint4*>((const u16*)hs + (size_t)(b*N_ + s)*64 + c0);
  uint4 uf = *reinterpret_cast<const uint4*>((const u16*)fe + (size_t)(b*E_ + e)*64 + c0);
  uint4 ud = *reinterpret_cast<const uint4*>((const u16*)hd + (size_t)(b*N_ + d2)*64 + c0);
  float w[8];
  if (f32) {
    float4 w0 = *reinterpret_cast<const float4*>((const float*)w_attn + c0);
    float4 w1 = *reinterpret_cast<const float4*>((const float*)w_attn + c0 + 4);
    w[0] = w0.x; w[1] = w0.y; w[2] = w0.z; w[3] = w0.w;
    w[4] = w1.x; w[5] = w1.y; w[6] = w1.z; w[7] = w1.w;
  } else {
    uint4 uw = *reinterpret_cast<const uint4*>((const u16*)w_attn + c0);
    w[0] = lo2f(uw.x); w[1] = hi2f(uw.x);
    w[2] = lo2f(uw.y); w[3] = hi2f(uw.y);
    w[4] = lo2f(uw.z); w[5] = hi2f(uw.z);
    w[6] = lo2f(uw.w); w[7] = hi2f(uw.w);
  }
  float v[8];
  v[0] = lo2f(ua.x) + lo2f(uf.x) + lo2f(ud.x);
  v[1] = hi2f(ua.x) + hi2f(uf.x) + hi2f(ud.x);
  v[2] = lo2f(ua.y) + lo2f(uf.y) + lo2f(ud.y);
  v[3] = hi2f(ua.y) + hi2f(uf.y) + hi2f(ud.y);
  v[4] = lo2f(ua.z) + lo2f(uf.z) + lo2f(ud.z);
  v[5] = hi2f(ua.z) + hi2f(uf.z) + hi2f(ud.z);
  v[6] = lo2f(ua.w) + lo2f(uf.w) + lo2f(ud.w);
  v[7] = hi2f(ua.w) + hi2f(uf.w) + hi2f(ud.w);
  float l = 0.f;
  #pragma unroll
  for (int j = 0; j < 8; ++j) {
    v[j] = v[j] > 0.f ? v[j] : 0.01f * v[j];
    l += v[j] * w[j];
  }
  size_t obase = (size_t)(b*OROW + p)*64 + c0;
  if (f32) {
    f32x4 o0; o0[0] = v[0]; o0[1] = v[1]; o0[2] = v[2]; o0[3] = v[3];
    f32x4 o1; o1[0] = v[4]; o1[1] = v[5]; o1[2] = v[6]; o1[3] = v[7];
    __builtin_nontemporal_store(o0, reinterpret_cast<f32x4*>((float*)out + obase));
    __builtin_nontemporal_store(o1, reinterpret_cast<f32x4*>((float*)out + obase + 4));
  } else {
    u32x4 o;
    o[0] = ((u32)f2bu(v[1]) << 16) | f2bu(v[0]);
    o[1] = ((u32)f2bu(v[3]) << 16) | f2bu(v[2]);
    o[2] = ((u32)f2bu(v[5]) << 16) | f2bu(v[4]);
    o[3] = ((u32)f2bu(v[7]) << 16) | f2bu(v[6]);
    __builtin_nontemporal_store(o, reinterpret_cast<u32x4*>((u16*)out + obase));
  }
  l += __shfl_down(l, 4, 8);
  l += __shfl_down(l, 2, 8);
  l += __shfl_down(l, 1, 8);
  if (sub == 0) {
    logits[b*P_ + p] = l;
    ld_log[wave * 8 + grp] = l;
  }
  __syncthreads();
  if (t < 32) {
    float li = ld_log[t];
    float m = li;
    #pragma unroll
    for (int o = 16; o > 0; o >>= 1) m = fmaxf(m, __shfl_xor(m, o, 32));
    float sv = __expf(li - m);
    #pragma unroll
    for (int o = 16; o > 0; o >>= 1) sv += __shfl_xor(sv, o, 32);
    if (t == 0) { mpart[chunk] = m; spart[chunk] = sv; }
  }
}

// ---------- Kernel C2: merge 500 partials per batch -> (M, 1/S) ----------
__global__ __launch_bounds__(256) void k_smerge(
    const float* __restrict__ mpart, const float* __restrict__ spart,
    float* __restrict__ mb, float* __restrict__ sb) {
  __shared__ float rm[256], rs[256];
  int b = blockIdx.x, t = threadIdx.x;
  float m = -1e30f, s = 0.f;
  for (int j = t; j < 500; j += 256) {
    float mj = mpart[500*b + j], sj = spart[500*b + j];
    float nm = fmaxf(m, mj);
    s = s * __expf(m - nm) + sj * __expf(mj - nm);
    m = nm;
  }
  rm[t] = m; rs[t] = s; __syncthreads();
  for (int st = 128; st > 0; st >>= 1) {
    if (t < st) {
      float mo = rm[t + st], so = rs[t + st];
      float nm = fmaxf(rm[t], mo);
      rs[t] = rs[t] * __expf(rm[t] - nm) + so * __expf(mo - nm);
      rm[t] = nm;
    }
    __syncthreads();
  }
  if (t == 0) { mb[b] = rm[0]; sb[b] = 1.0f / rs[0]; }
}

// ---------- Kernel D: h_out ----------
// grid (N_, 4), block 256 = 4 waves (one batch each). rowptr gives the node's
// edge range; 4 edge-groups x 16 ch gather-dot; xor-reduce across groups.
// Nontemporal out stores (out is write-only for us).
__global__ __launch_bounds__(256) void k_hout(
    const int* __restrict__ flags,
    const bf16* __restrict__ h, const float* __restrict__ logits,
    const float* __restrict__ mb, const float* __restrict__ sb,
    const int* __restrict__ rowptr, const int* __restrict__ dst,
    void* __restrict__ out) {
  const int f32 = flags[0];
  int n = blockIdx.x;
  int t = threadIdx.x;
  int wave = t >> 6, lane = t & 63;
  int b = blockIdx.y * 4 + wave;
  float m = mb[b], inv = sb[b];
  int start = rowptr[n], end = rowptr[n + 1];
  int grp = lane >> 4, sub = lane & 15, c0 = sub * 4;
  float a0 = 0.f, a1 = 0.f, a2 = 0.f, a3 = 0.f;
  for (int p = start + grp; p < end; p += 4) {
    float a = __expf(logits[b*P_ + p] - m) * inv;
    int dn = dst[p];
    ushort4 hv = *reinterpret_cast<const ushort4*>((const u16*)h + (size_t)(b*N_ + dn)*64 + c0);
    a0 += a * u2f(hv.x); a1 += a * u2f(hv.y);
    a2 += a * u2f(hv.z); a3 += a * u2f(hv.w);
  }
  a0 += __shfl_xor(a0, 16, 64); a0 += __shfl_xor(a0, 32, 64);
  a1 += __shfl_xor(a1, 16, 64); a1 += __shfl_xor(a1, 32, 64);
  a2 += __shfl_xor(a2, 16, 64); a2 += __shfl_xor(a2, 32, 64);
  a3 += __shfl_xor(a3, 16, 64); a3 += __shfl_xor(a3, 32, 64);
  if (grp == 0) {
    size_t obase = (size_t)(b*OROW + P_ + n)*64 + c0;
    if (f32) {
      f32x4 o4; o4[0] = a0; o4[1] = a1; o4[2] = a2; o4[3] = a3;
      __builtin_nontemporal_store(o4, reinterpret_cast<f32x4*>((float*)out + obase));
    } else {
      u16x4 o4;
      o4[0] = f2bu(a0); o4[1] = f2bu(a1); o4[2] = f2bu(a2); o4[3] = f2bu(a3);
      __builtin_nontemporal_store(o4, reinterpret_cast<u16x4*>((u16*)out + obase));
    }
  }
}

extern "C" void kernel_launch(void* const* d_in, const int* in_sizes, int n_in,
                              void* d_out, int out_size, void* d_ws, size_t ws_size,
                              hipStream_t stream) {
  const void* x      = d_in[0];
  const void* W_edge = d_in[1];
  const void* W_node = d_in[2];
  const void* b_node = d_in[3];
  const void* W_comb = d_in[4];
  const void* b_comb = d_in[5];
  const void* w_attn = d_in[6];
  const int* src  = (const int*)d_in[7];
  const int* dst  = (const int*)d_in[8];
  const int* eidx = (const int*)d_in[9];

  // workspace layout (f32 units)
  float* logits = (float*)d_ws;          // 256000
  float* mpart  = logits + B_*P_;        // 8000
  float* spart  = mpart + 8000;          // 8000
  float* mb     = spart + 8000;          // 16
  float* sb     = mb + B_;               // 16
  float* c1     = sb + B_;               // 64
  float* c3     = c1 + 64;               // 64
  int*   rowptr = (int*)(c3 + 64);       // 2016 (padded)
  int*   flags  = rowptr + 2016;         // 16 (dtype flag, padded)
  u16*   Wtn    = (u16*)(flags + 16);    // 192*64
  u16*   Wte    = Wtn + 192*64;          // 64*64
  bf16*  h      = (bf16*)(Wte + 64*64);  // B*N*64
  bf16*  hs     = h  + B_*N_*64;
  bf16*  hd     = hs + B_*N_*64;
  bf16*  fe     = hd + B_*N_*64;         // B*E*64

  k_pre<<<73, 256, 0, stream>>>(x, W_edge, W_node, b_node, W_comb, b_comb, src, Wtn, Wte, c1, c3, rowptr, flags);
  k_transform<<<1500, 256, 0, stream>>>(x, flags, Wtn, Wte, b_node, c1, c3, h, hs, hd, fe);
  k_combine<<<(B_*P_)/32, 256, 0, stream>>>(flags, hs, hd, fe, w_attn, src, dst, eidx, d_out, logits, mpart, spart);
  k_smerge<<<B_, 256, 0, stream>>>(mpart, spart, mb, sb);
  k_hout<<<dim3(N_, B_/4), 256, 0, stream>>>(flags, h, logits, mb, sb, rowptr, dst, d_out);
}